// Round 1
// baseline (13929.710 us; speedup 1.0000x reference)
//
#include <hip/hip_runtime.h>
#include <math.h>

#define VV 32000
#define EE 256
#define HH 512
#define SS 400
#define TT 100
#define BB 32

// ---- workspace layout (float offsets) ----
#define WS_HPP   0u                       // 2 * 32*512 = 32768 (encoder h ping-pong)
#define WS_HALL  32768u                   // 100*32*512 = 1638400 (decoder h after each step)
#define WS_OE    (32768u + 1638400u)      // 3200*256 = 819200
#define WS_M     (WS_OE + 819200u)        // 125*3200 = 400000 (slice max)
#define WS_ZZ    (WS_M + 400000u)         // 400000 (slice expsum)
#define WS_AM    (WS_ZZ + 400000u)        // 400000 (slice argmax, uint)
#define WS_GOLD  (WS_AM + 400000u)        // 3200 (gold logit per row)
#define WS_NLL   (WS_GOLD + 3200u)        // 3200
// total = 3696768 floats = ~14.8 MB

__global__ __launch_bounds__(256) void k_zero(float* p, int n) {
    int i = blockIdx.x * 256 + threadIdx.x;
    if (i < n) p[i] = 0.f;
}

// One GRU step: h_out = GRUCell(emb[tok], h_in).
// grid 64 blocks x 768 threads. block = 16 batches x 16 h-cols x 3 K-slices.
// K-slice 0 = x part (K=256, W_ih), slices 1,2 = h halves (W_hh).
__global__ __launch_bounds__(768) void k_gru(
    const float* __restrict__ emb, const int* __restrict__ tok, int sos,
    const float* __restrict__ Wih, const float* __restrict__ Whh,
    const float* __restrict__ bih, const float* __restrict__ bhh,
    const float* __restrict__ h_in, float* __restrict__ h_out)
{
    __shared__ float z[16][772];            // [batch][x(0..255) | h(256..767)], pad->772
    __shared__ float part[3][3][16][16];    // [kp][gate][c][b]
    const int tid = threadIdx.x;
    const int cblk = blockIdx.x & 31;       // 32 col-blocks of 16 cols
    const int bg0 = (blockIdx.x >> 5) * 16; // 2 batch halves

    // stage x (gathered embedding) and h into LDS: 3072 float4 chunks / 768 thr = 4 each
    #pragma unroll
    for (int i = 0; i < 4; ++i) {
        int idx = tid + i * 768;
        if (idx < 1024) {
            int bl = idx >> 6, k4 = idx & 63;
            int tk = sos ? 1 : tok[bg0 + bl];
            *(float4*)&z[bl][k4 * 4] = *(const float4*)(emb + (size_t)tk * EE + k4 * 4);
        } else {
            int j = idx - 1024;
            int bl = j >> 7, k4 = j & 127;
            *(float4*)&z[bl][256 + k4 * 4] = *(const float4*)(h_in + (bg0 + bl) * HH + k4 * 4);
        }
    }
    __syncthreads();

    const int b  = tid & 15;
    const int c  = (tid >> 4) & 15;
    const int kp = tid >> 8;                // 0..2
    const int cg = cblk * 16 + c;           // global h-col 0..511

    const float *w0, *w1, *w2; int koff;
    if (kp == 0) {
        w0 = Wih + (size_t)(0 * HH + cg) * EE;
        w1 = Wih + (size_t)(1 * HH + cg) * EE;
        w2 = Wih + (size_t)(2 * HH + cg) * EE;
        koff = 0;
    } else {
        int o = (kp == 1) ? 0 : 256;
        w0 = Whh + (size_t)(0 * HH + cg) * HH + o;
        w1 = Whh + (size_t)(1 * HH + cg) * HH + o;
        w2 = Whh + (size_t)(2 * HH + cg) * HH + o;
        koff = 256 + o;
    }

    float a0 = 0.f, a1 = 0.f, a2 = 0.f;
    #pragma unroll 8
    for (int k4 = 0; k4 < 64; ++k4) {
        float4 zv = *(const float4*)&z[b][koff + k4 * 4];
        float4 v0 = *(const float4*)(w0 + k4 * 4);
        float4 v1 = *(const float4*)(w1 + k4 * 4);
        float4 v2 = *(const float4*)(w2 + k4 * 4);
        a0 += zv.x * v0.x + zv.y * v0.y + zv.z * v0.z + zv.w * v0.w;
        a1 += zv.x * v1.x + zv.y * v1.y + zv.z * v1.z + zv.w * v1.w;
        a2 += zv.x * v2.x + zv.y * v2.y + zv.z * v2.z + zv.w * v2.w;
    }
    part[kp][0][c][b] = a0;
    part[kp][1][c][b] = a1;
    part[kp][2][c][b] = a2;
    __syncthreads();

    if (kp == 0) {
        float gr  = part[0][0][c][b] + part[1][0][c][b] + part[2][0][c][b];
        float gz  = part[0][1][c][b] + part[1][1][c][b] + part[2][1][c][b];
        float gin = part[0][2][c][b];                       // x part of n-gate (has b_ih)
        float ghn = part[1][2][c][b] + part[2][2][c][b];    // h part of n-gate (has b_hh)
        float r  = 1.f / (1.f + expf(-(gr + bih[cg] + bhh[cg])));
        float zg = 1.f / (1.f + expf(-(gz + bih[HH + cg] + bhh[HH + cg])));
        float n  = tanhf(gin + bih[2 * HH + cg] + r * (ghn + bhh[2 * HH + cg]));
        float hp = z[b][256 + cg];
        h_out[(bg0 + b) * HH + cg] = (1.f - zg) * n + zg * hp;
    }
}

// OE[r][c] = dot(Hall[r][:512], preW[c][:512]) + preb[c].  grid (4, 200) x 256 thr.
__global__ __launch_bounds__(256) void k_outemb(
    const float* __restrict__ Hall, const float* __restrict__ preW,
    const float* __restrict__ preb, float* __restrict__ OE)
{
    __shared__ float hs[16][516];
    const int tid = threadIdx.x;
    const int c0 = blockIdx.x * 64;
    const int r0 = blockIdx.y * 16;
    #pragma unroll
    for (int i = 0; i < 8; ++i) {
        int idx = tid + i * 256;            // 2048 = 16 rows * 128 vec4
        int rr = idx >> 7, k4 = idx & 127;
        *(float4*)&hs[rr][k4 * 4] = *(const float4*)(Hall + (size_t)(r0 + rr) * HH + k4 * 4);
    }
    __syncthreads();
    const int rr = tid & 15, cc = tid >> 4;
    int cj[4]; float acc[4];
    #pragma unroll
    for (int j = 0; j < 4; ++j) { cj[j] = c0 + cc + 16 * j; acc[j] = preb[cj[j]]; }
    for (int k4 = 0; k4 < 128; ++k4) {
        float4 hv = *(const float4*)&hs[rr][k4 * 4];
        #pragma unroll
        for (int j = 0; j < 4; ++j) {
            float4 wv = *(const float4*)(preW + (size_t)cj[j] * HH + k4 * 4);
            acc[j] += hv.x * wv.x + hv.y * wv.y + hv.z * wv.z + hv.w * wv.w;
        }
    }
    #pragma unroll
    for (int j = 0; j < 4; ++j) OE[(size_t)(r0 + rr) * EE + cj[j]] = acc[j];
}

// Fused tied-embedding logits + online-softmax slice partials.
// grid (125 col-slices, 100 row-tiles) x 128 thr. Block tile: 32 rows x 256 cols, K=256.
// Thread tile 8x8. Never materializes logits.
__global__ __launch_bounds__(128) void k_logits(
    const float* __restrict__ OE, const float* __restrict__ emb,
    const float* __restrict__ outb, const int* __restrict__ tgt,
    float* __restrict__ m_arr, float* __restrict__ z_arr,
    unsigned int* __restrict__ am_arr, float* __restrict__ gold_arr)
{
    __shared__ float oes[32][260];
    __shared__ float ems[256][18];          // 16-k chunk, pitch 18 (2-way = free)
    const int tid = threadIdx.x;
    const int c0 = blockIdx.x * 256;
    const int r0 = blockIdx.y * 32;

    #pragma unroll
    for (int i = 0; i < 16; ++i) {
        int idx = tid + i * 128;            // 2048 = 32 rows * 64 vec4
        int rr2 = idx >> 6, k4 = idx & 63;
        *(float4*)&oes[rr2][k4 * 4] = *(const float4*)(OE + (size_t)(r0 + rr2) * EE + k4 * 4);
    }

    const int rr  = tid >> 5;               // 0..3, rows rr*8 + i
    const int ccg = tid & 31;               // cols ccg + 32j
    float acc[8][8];
    #pragma unroll
    for (int i = 0; i < 8; ++i)
        #pragma unroll
        for (int j = 0; j < 8; ++j) acc[i][j] = 0.f;

    for (int kc = 0; kc < 16; ++kc) {
        __syncthreads();                    // oes ready (kc=0) / prev ems reads done
        #pragma unroll
        for (int i = 0; i < 16; ++i) {
            int idx = tid + i * 128;        // 2048 = 256 cols * 8 float2
            int col = idx >> 3, f2 = idx & 7;
            *(float2*)&ems[col][f2 * 2] =
                *(const float2*)(emb + (size_t)(c0 + col) * EE + kc * 16 + f2 * 2);
        }
        __syncthreads();
        #pragma unroll
        for (int kk = 0; kk < 16; kk += 4) {
            float4 ov[8];
            #pragma unroll
            for (int i = 0; i < 8; ++i) ov[i] = *(const float4*)&oes[rr * 8 + i][kc * 16 + kk];
            #pragma unroll
            for (int j = 0; j < 8; ++j) {
                float2 e0 = *(const float2*)&ems[ccg + 32 * j][kk];
                float2 e1 = *(const float2*)&ems[ccg + 32 * j][kk + 2];
                #pragma unroll
                for (int i = 0; i < 8; ++i)
                    acc[i][j] += ov[i].x * e0.x + ov[i].y * e0.y + ov[i].z * e1.x + ov[i].w * e1.y;
            }
        }
    }

    // epilogue: + out_b, slice max/argmax/expsum, gold logit
    #pragma unroll
    for (int i = 0; i < 8; ++i) {
        int r = r0 + rr * 8 + i;
        int gold = tgt[r];                  // target flat index == row index
        float vals[8]; float m = -3.4e38f; int cb = 0x7fffffff;
        #pragma unroll
        for (int j = 0; j < 8; ++j) {
            int cj = c0 + ccg + 32 * j;
            float v = acc[i][j] + outb[cj];
            vals[j] = v;
            if (v > m) { m = v; cb = cj; }
            if (cj == gold) gold_arr[r] = v;
        }
        for (int mk = 1; mk <= 16; mk <<= 1) {   // reduce over 32 ccg lanes (half-wave)
            float mo = __shfl_xor(m, mk);
            int   co = __shfl_xor(cb, mk);
            if (mo > m || (mo == m && co < cb)) { m = mo; cb = co; }
        }
        float s = 0.f;
        #pragma unroll
        for (int j = 0; j < 8; ++j) s += expf(vals[j] - m);
        for (int mk = 1; mk <= 16; mk <<= 1) s += __shfl_xor(s, mk);
        if (ccg == 0) {
            size_t p = (size_t)blockIdx.x * 3200 + r;
            m_arr[p] = m; z_arr[p] = s; am_arr[p] = (unsigned)cb;
        }
    }
}

// Merge 125 slice partials per row; write token (float) and nll.
__global__ __launch_bounds__(256) void k_merge(
    const float* __restrict__ m_arr, const float* __restrict__ z_arr,
    const unsigned* __restrict__ am_arr, const float* __restrict__ gold_arr,
    float* __restrict__ nll, float* __restrict__ out)
{
    int r = blockIdx.x * 256 + threadIdx.x;
    if (r >= 3200) return;
    float M = -3.4e38f, Z = 0.f, bm = -3.4e38f; unsigned bc = 0u;
    for (int s = 0; s < 125; ++s) {
        size_t p = (size_t)s * 3200 + r;
        float ms = m_arr[p]; float zs = z_arr[p]; unsigned cs = am_arr[p];
        if (ms > M) { Z = Z * expf(M - ms) + zs; M = ms; }
        else        { Z += zs * expf(ms - M); }
        if (ms > bm || (ms == bm && cs < bc)) { bm = ms; bc = cs; }
    }
    float pg = expf(gold_arr[r] - M) / Z;
    nll[r] = -logf(pg + 1e-20f);
    out[r] = (float)bc;
}

// Per-step masked mean nll, then total. One block of 128.
__global__ __launch_bounds__(128) void k_loss(
    const float* __restrict__ nll, const int* __restrict__ tgt, float* __restrict__ out)
{
    __shared__ float ls[128];
    int t = threadIdx.x;
    float lt = 0.f;
    if (t < TT) {
        float s = 0.f; int cnt = 0;
        for (int b = 0; b < BB; ++b) {
            int g = tgt[t * BB + b];
            if (g != 0) { s += nll[t * BB + b]; cnt++; }
        }
        lt = s / fmaxf((float)cnt, 1.f);
    }
    ls[t] = lt;
    __syncthreads();
    for (int off = 64; off > 0; off >>= 1) {
        if (t < off) ls[t] += ls[t + off];
        __syncthreads();
    }
    if (t == 0) out[3200] = ls[0];
}

extern "C" void kernel_launch(void* const* d_in, const int* in_sizes, int n_in,
                              void* d_out, int out_size, void* d_ws, size_t ws_size,
                              hipStream_t stream) {
    const int*   src  = (const int*)  d_in[0];
    const int*   tgt  = (const int*)  d_in[1];
    const float* emb  = (const float*)d_in[2];
    const float* eWih = (const float*)d_in[3];
    const float* eWhh = (const float*)d_in[4];
    const float* ebih = (const float*)d_in[5];
    const float* ebhh = (const float*)d_in[6];
    const float* dWih = (const float*)d_in[7];
    const float* dWhh = (const float*)d_in[8];
    const float* dbih = (const float*)d_in[9];
    const float* dbhh = (const float*)d_in[10];
    const float* preW = (const float*)d_in[11];
    const float* preb = (const float*)d_in[12];
    const float* outb = (const float*)d_in[13];

    float* ws   = (float*)d_ws;
    float* out  = (float*)d_out;
    float* hpp  = ws + WS_HPP;
    float* Hall = ws + WS_HALL;
    float* OE   = ws + WS_OE;
    float* m_a  = ws + WS_M;
    float* z_a  = ws + WS_ZZ;
    unsigned* am_a = (unsigned*)(ws + WS_AM);
    float* gold = ws + WS_GOLD;
    float* nll  = ws + WS_NLL;

    // h0 = 0 (ws is poisoned 0xAA before every call)
    k_zero<<<64, 256, 0, stream>>>(hpp, BB * HH);

    // encoder: 400 sequential steps, ping-pong h
    for (int t = 0; t < SS; ++t) {
        const float* hin = hpp + (t & 1) * (BB * HH);
        float* hout      = hpp + ((t + 1) & 1) * (BB * HH);
        k_gru<<<64, 768, 0, stream>>>(emb, src + t * BB, 0,
                                      eWih, eWhh, ebih, ebhh, hin, hout);
    }
    // after 400 steps final h is in hpp[0]

    // decoder recurrence: h_{t+1} stored to Hall[t]
    for (int t = 0; t < TT; ++t) {
        const float* hin = (t == 0) ? hpp : (Hall + (size_t)(t - 1) * BB * HH);
        float* hout      = Hall + (size_t)t * BB * HH;
        const int* tp    = (t == 0) ? src : (tgt + (t - 1) * BB);  // t==0 uses SOS flag
        k_gru<<<64, 768, 0, stream>>>(emb, tp, (t == 0) ? 1 : 0,
                                      dWih, dWhh, dbih, dbhh, hin, hout);
    }

    // batched output path
    k_outemb<<<dim3(4, 200), 256, 0, stream>>>(Hall, preW, preb, OE);
    k_logits<<<dim3(125, 100), 128, 0, stream>>>(OE, emb, outb, tgt, m_a, z_a, am_a, gold);
    k_merge<<<13, 256, 0, stream>>>(m_a, z_a, am_a, gold, nll, out);
    k_loss<<<1, 128, 0, stream>>>(nll, tgt, out);
}